// Round 3
// baseline (481.727 us; speedup 1.0000x reference)
//
#include <hip/hip_runtime.h>
#include <hip/hip_bf16.h>
#include <math.h>

#define MODES 32
#define IN_CH 32
#define OUT_CH 32
#define SIZE 2048
#define BATCH 8
#define SM1 2047.0f

// ws float-index layout:
//   0     : xmean[32]
//   32    : poles[32]
//   64    : d[32]            d = exp(-p/2047)
//   96    : dW1[32]          d^(W+1)
//   128   : pf[32]           spectral filter
//   160   : (int) W
//   256   : xsum[8][2048]    (16384)   Σ_c x[b,c,s]
//   32768 : scale[2048][32]  (65536)   pf[k]/rownorm[k,t]
//   98304 : wsum[32][32]     (1024)    Σ_i sigmoid(wla)*cos(wph), [k][o]
//   131072: zF[8][2048][32]  (524288)
//   655360: zB[8][2048][32]  (524288)
// total ~4.7 MB

__global__ void k_xmean(const float* __restrict__ x, float* __restrict__ ws) {
    int c = blockIdx.x;
    float s = 0.f;
    for (int i = threadIdx.x; i < BATCH * SIZE; i += 256) {
        int b = i >> 11, t = i & (SIZE - 1);
        s += x[(b * IN_CH + c) * SIZE + t];
    }
    __shared__ float red[256];
    red[threadIdx.x] = s;
    __syncthreads();
    for (int off = 128; off > 0; off >>= 1) {
        if (threadIdx.x < off) red[threadIdx.x] += red[threadIdx.x + off];
        __syncthreads();
    }
    if (threadIdx.x == 0) ws[c] = red[0] * (1.0f / (BATCH * SIZE));
}

__global__ void k_xsum(const float* __restrict__ x, float* __restrict__ ws) {
    int gid = blockIdx.x * 256 + threadIdx.x;   // 16384 = B*S
    int b = gid >> 11, s = gid & (SIZE - 1);
    float a = 0.f;
#pragma unroll
    for (int c = 0; c < IN_CH; ++c) a += x[(b * IN_CH + c) * SIZE + s];
    ws[256 + gid] = a;
}

__global__ void k_prep(const float* __restrict__ c_star, const float* __restrict__ dt,
                       const float* __restrict__ log_poles, const float* __restrict__ pole_w,
                       const float* __restrict__ pole_b, float* __restrict__ ws) {
    int k = threadIdx.x;
    float mc = c_star[0];
    for (int b = 1; b < BATCH; ++b) mc = fmaxf(mc, c_star[b]);
    float mdn = mc * dt[0];  // CAUSAL_SAFETY = 1
    int W = (int)(mdn * SM1);
    while (W + 1 <= SIZE - 1 && (float)(W + 1) / SM1 <= mdn) ++W;
    while (W > 0 && (float)W / SM1 > mdn) --W;
    if (W > SIZE - 1) W = SIZE - 1;
    if (W < 0) W = 0;
    if (k == 0) ((int*)ws)[160] = W;
    if (k < MODES) {
        float acc = pole_b[k];
        for (int c = 0; c < IN_CH; ++c) acc += ws[c] * pole_w[c * MODES + k];
        float off = tanhf(acc);
        float z = log_poles[k] + 0.1f * off;          // POLE_OFF_SCALE
        float p = log1pf(expf(z));                    // softplus
        p = fminf(fmaxf(p, 0.1f), 100.0f);
        ws[32 + k] = p;
        ws[64 + k] = expf(-p / SM1);
        ws[96 + k] = expf(-p * (float)(W + 1) / SM1);
        float kn = (float)k / 31.0f;
        ws[128 + k] = expf(-4.0f * kn * kn);          // FILTER_STRENGTH
    }
}

__global__ void k_wsum(const float* __restrict__ wla, const float* __restrict__ wph,
                       float* __restrict__ ws) {
    int tid = threadIdx.x;            // 1024 = k*32+o
    int k = tid >> 5, o = tid & 31;
    float a = 0.f;
#pragma unroll 4
    for (int c = 0; c < IN_CH; ++c) {
        int e = (k * IN_CH + c) * OUT_CH + o;
        float amp = 1.0f / (1.0f + expf(-wla[e]));    // MAX_AMP=1, AMP_SHARP=1
        a += amp * cosf(wph[e]);
    }
    ws[98304 + tid] = a;
}

__global__ void k_scale(float* __restrict__ ws) {
    int gid = blockIdx.x * 256 + threadIdx.x;  // gid = t*32 + k
    if (gid >= SIZE * MODES) return;
    int k = gid & 31, t = gid >> 5;
    int W = ((const int*)ws)[160];
    float p = ws[32 + k];
    float d = ws[64 + k];
    float pf = ws[128 + k];
    float den = -expm1f(-p / SM1);  // 1 - d
    int n1 = min(W, t), n2 = min(W, SIZE - 1 - t);
    float g1 = d * (-expm1f(-p * (float)n1 / SM1)) / den;
    float g2 = d * (-expm1f(-p * (float)n2 / SM1)) / den;
    float rn = 1.0f + g1 + g2;      // >= 1, reference clip(1e-8) no-op
    ws[32768 + gid] = pf / rn;
}

// grid 4, block 128. wave0 = forward, wave1 = backward; sub-half of each wave = one of 2 batches.
__global__ void k_rec(const float* __restrict__ ws, float* __restrict__ zF,
                      float* __restrict__ zB) {
    __shared__ float xs[2 * SIZE];
    int tid = threadIdx.x;
    for (int i = tid; i < 2 * SIZE; i += 128) xs[i] = ws[256 + blockIdx.x * 2 * SIZE + i];
    __syncthreads();
    int half = tid >> 6;             // 0 fwd, 1 bwd (wave-uniform)
    int sub = (tid >> 5) & 1;        // batch within block
    int k = tid & 31;
    int b = blockIdx.x * 2 + sub;
    int W = ((const int*)ws)[160];
    float d = ws[64 + k], dW1 = ws[96 + k];
    const float* sc = ws + 32768;
    const float* xr = xs + sub * SIZE;
    if (half == 0) {
        float F = 0.f;
        float* out = zF + (size_t)b * SIZE * 32 + k;
#pragma unroll 4
        for (int t = 0; t < SIZE; ++t) {
            float u = xr[t];
            int tl = t - W - 1;
            if (tl >= 0) u = fmaf(-dW1, xr[tl], u);
            F = fmaf(d, F, u);
            out[t * 32] = F * sc[t * 32 + k];
        }
    } else {
        float B = 0.f;
        float* out = zB + (size_t)b * SIZE * 32 + k;
        out[(SIZE - 1) * 32] = 0.f;
#pragma unroll 4
        for (int t = SIZE - 2; t >= 0; --t) {
            B = d * (B + xr[t + 1]);
            int th = t + W + 1;
            if (th <= SIZE - 1) B = fmaf(-dW1, xr[th], B);
            out[t * 32] = B * sc[t * 32 + k];
        }
    }
}

// out[b,o,t] = sum_k (zF+zB)[b,t,k] * wsum[k,o]   — f32 output
__global__ void k_out(const float* __restrict__ ws, const float* __restrict__ zF,
                      const float* __restrict__ zB, float* __restrict__ out) {
    __shared__ float wl[MODES * OUT_CH];
    int tid = threadIdx.x;
    for (int i = tid; i < MODES * OUT_CH; i += 256) wl[i] = ws[98304 + i];
    __syncthreads();
    int o = tid & 31;
    int row = blockIdx.x * 8 + (tid >> 5);    // row = b*SIZE + t
    const float* zf = zF + (size_t)row * 32;
    const float* zb = zB + (size_t)row * 32;
    float acc = 0.f;
#pragma unroll
    for (int k = 0; k < MODES; ++k) acc = fmaf(zf[k] + zb[k], wl[k * 32 + o], acc);
    int b = row >> 11, t = row & (SIZE - 1);
    out[(b * OUT_CH + o) * SIZE + t] = acc;
}

extern "C" void kernel_launch(void* const* d_in, const int* in_sizes, int n_in,
                              void* d_out, int out_size, void* d_ws, size_t ws_size,
                              hipStream_t stream) {
    const float* x      = (const float*)d_in[0];
    const float* c_star = (const float*)d_in[1];
    const float* dt     = (const float*)d_in[2];
    // d_in[3] = dx_star (unused by the forward)
    const float* wla    = (const float*)d_in[4];
    const float* wph    = (const float*)d_in[5];
    const float* lp     = (const float*)d_in[6];
    const float* pw     = (const float*)d_in[7];
    const float* pb     = (const float*)d_in[8];
    float* out = (float*)d_out;                 // reference output dtype = float32
    float* ws  = (float*)d_ws;
    float* zF  = ws + 131072;
    float* zB  = ws + 655360;

    k_xmean<<<32,   256,  0, stream>>>(x, ws);
    k_xsum <<<64,   256,  0, stream>>>(x, ws);
    k_prep <<<1,    64,   0, stream>>>(c_star, dt, lp, pw, pb, ws);
    k_wsum <<<1,    1024, 0, stream>>>(wla, wph, ws);
    k_scale<<<256,  256,  0, stream>>>(ws);
    k_rec  <<<4,    128,  0, stream>>>(ws, zF, zB);
    k_out  <<<2048, 256,  0, stream>>>(ws, zF, zB, out);
}

// Round 4
// 61.933 us; speedup vs baseline: 7.7782x; 7.7782x over previous
//
#include <hip/hip_runtime.h>
#include <hip/hip_bf16.h>
#include <math.h>

#define MODES 32
#define IN_CH 32
#define OUT_CH 32
#define SIZE 2048
#define BATCH 8
#define SM1 2047.0f
#define CHUNK 64           // scan chunk length L
#define NCHUNK 32          // SIZE / CHUNK

// ws float-index layout:
//   0      : xmean[32]
//   32     : poles[32]
//   64     : d[32]              d = exp(-p/2047)
//   96     : dW1[32]            d^(W+1)
//   128    : pf[32]             spectral filter
//   160    : (int) W
//   256    : xsum[8][2048]      (16384)
//   16640  : scale[2048][32]    (65536)  pf[k]/rownorm[k,t]
//   82176  : wsum[32][32]       (1024)   [k][o]
//   83200  : finLocal[2][8][32][32] (16384)  chunk-local final state
//   99584  : Fin[2][8][32][32]      (16384)  carry-in per chunk
//   115968 : pw1[64][32]        (2048)   d^(i+1)
//   118016 : pw2[64][32]        (2048)   d^(64-i)
//   120064 : zF[8][2048][32]    (524288)  (after k_fix: final y)
//   644352 : zB[8][2048][32]    (524288)
// top = 1168640 floats = 4.67 MB

__global__ void k_xmean(const float* __restrict__ x, float* __restrict__ ws) {
    int c = blockIdx.x;
    float s = 0.f;
    for (int i = threadIdx.x; i < BATCH * SIZE; i += 256) {
        int b = i >> 11, t = i & (SIZE - 1);
        s += x[(b * IN_CH + c) * SIZE + t];
    }
    __shared__ float red[256];
    red[threadIdx.x] = s;
    __syncthreads();
    for (int off = 128; off > 0; off >>= 1) {
        if (threadIdx.x < off) red[threadIdx.x] += red[threadIdx.x + off];
        __syncthreads();
    }
    if (threadIdx.x == 0) ws[c] = red[0] * (1.0f / (BATCH * SIZE));
}

__global__ void k_xsum(const float* __restrict__ x, float* __restrict__ ws) {
    int gid = blockIdx.x * 256 + threadIdx.x;   // 16384 = B*S
    int b = gid >> 11, s = gid & (SIZE - 1);
    float a = 0.f;
#pragma unroll
    for (int c = 0; c < IN_CH; ++c) a += x[(b * IN_CH + c) * SIZE + s];
    ws[256 + gid] = a;
}

__global__ void k_prep(const float* __restrict__ c_star, const float* __restrict__ dt,
                       const float* __restrict__ log_poles, const float* __restrict__ pole_w,
                       const float* __restrict__ pole_b, float* __restrict__ ws) {
    int k = threadIdx.x;
    float mc = c_star[0];
    for (int b = 1; b < BATCH; ++b) mc = fmaxf(mc, c_star[b]);
    float mdn = mc * dt[0];  // CAUSAL_SAFETY = 1
    int W = (int)(mdn * SM1);
    while (W + 1 <= SIZE - 1 && (float)(W + 1) / SM1 <= mdn) ++W;
    while (W > 0 && (float)W / SM1 > mdn) --W;
    if (W > SIZE - 1) W = SIZE - 1;
    if (W < 0) W = 0;
    if (k == 0) ((int*)ws)[160] = W;
    if (k < MODES) {
        float acc = pole_b[k];
        for (int c = 0; c < IN_CH; ++c) acc += ws[c] * pole_w[c * MODES + k];
        float off = tanhf(acc);
        float z = log_poles[k] + 0.1f * off;          // POLE_OFF_SCALE
        float p = log1pf(expf(z));                    // softplus
        p = fminf(fmaxf(p, 0.1f), 100.0f);
        ws[32 + k] = p;
        ws[64 + k] = expf(-p / SM1);
        ws[96 + k] = expf(-p * (float)(W + 1) / SM1);
        float kn = (float)k / 31.0f;
        ws[128 + k] = expf(-4.0f * kn * kn);          // FILTER_STRENGTH
    }
}

__global__ void k_wsum(const float* __restrict__ wla, const float* __restrict__ wph,
                       float* __restrict__ ws) {
    int tid = threadIdx.x;            // 1024 = k*32+o
    int k = tid >> 5, o = tid & 31;
    float a = 0.f;
#pragma unroll 4
    for (int c = 0; c < IN_CH; ++c) {
        int e = (k * IN_CH + c) * OUT_CH + o;
        float amp = 1.0f / (1.0f + expf(-wla[e]));    // MAX_AMP=1, AMP_SHARP=1
        a += amp * cosf(wph[e]);
    }
    ws[82176 + tid] = a;
}

// scale table + chunk power tables
__global__ void k_scale(float* __restrict__ ws) {
    int gid = blockIdx.x * 256 + threadIdx.x;  // gid = t*32 + k, 65536 total
    int k = gid & 31, t = gid >> 5;
    int W = ((const int*)ws)[160];
    float p = ws[32 + k];
    float d = ws[64 + k];
    float pf = ws[128 + k];
    float den = -expm1f(-p / SM1);  // 1 - d
    int n1 = min(W, t), n2 = min(W, SIZE - 1 - t);
    float g1 = d * (-expm1f(-p * (float)n1 / SM1)) / den;
    float g2 = d * (-expm1f(-p * (float)n2 / SM1)) / den;
    float rn = 1.0f + g1 + g2;
    ws[16640 + gid] = pf / rn;
    if (gid < CHUNK * 32) {
        int i = gid >> 5;
        ws[115968 + gid] = expf(-p * (float)(i + 1) / SM1);   // d^(i+1)
        ws[118016 + gid] = expf(-p * (float)(CHUNK - i) / SM1); // d^(L-i)
    }
}

// chunk-local scans: 16384 threads = (b, dir, chunk, k)
__global__ void k_scan(float* __restrict__ ws) {
    int g = blockIdx.x * 256 + threadIdx.x;
    int k = g & 31;
    int r = g >> 5;
    int chunk = r & (NCHUNK - 1);
    int dir = (r >> 5) & 1;
    int b = r >> 6;
    int W = ((const int*)ws)[160];
    float d = ws[64 + k], dW1 = ws[96 + k];
    const float* xr = ws + 256 + b * SIZE;
    float* zF = ws + 120064;
    float* zB = ws + 644352;
    float st = 0.f;
    if (dir == 0) {
        int t0 = chunk * CHUNK;
#pragma unroll 4
        for (int i = 0; i < CHUNK; ++i) {
            int t = t0 + i;
            float u = xr[t];
            int tl = t - W - 1;
            if (tl >= 0) u = fmaf(-dW1, xr[tl], u);
            st = fmaf(d, st, u);
            zF[(size_t)((b << 11) + t) * 32 + k] = st;
        }
    } else {
        int t1 = chunk * CHUNK + CHUNK - 1;
#pragma unroll 4
        for (int i = 0; i < CHUNK; ++i) {
            int t = t1 - i;
            float u = xr[t];
            int th = t + W + 1;
            if (th <= SIZE - 1) u = fmaf(-dW1, xr[th], u);
            st = fmaf(d, st, u);
            zB[(size_t)((b << 11) + t) * 32 + k] = st;
        }
    }
    ws[83200 + dir * 8192 + ((b * 32 + k) << 5) + chunk] = st;
}

// carry combine: 512 threads = (dir, b, k); 32 serial steps each
__global__ void k_carry(float* __restrict__ ws) {
    int tid = threadIdx.x;
    int k = tid & 31, b = (tid >> 5) & 7, dir = tid >> 8;
    float p = ws[32 + k];
    float dL = expf(-p * (float)CHUNK / SM1);
    const float* loc = ws + 83200 + dir * 8192 + ((b * 32 + k) << 5);
    float* fin = ws + 99584 + dir * 8192 + ((b * 32 + k) << 5);
    float T = 0.f;
    if (dir == 0) {
        for (int c = 0; c < NCHUNK; ++c) { fin[c] = T; T = fmaf(dL, T, loc[c]); }
    } else {
        for (int c = NCHUNK - 1; c >= 0; --c) { fin[c] = T; T = fmaf(dL, T, loc[c]); }
    }
}

// fixup + scale: y = (zF + d^(i+1)*FinF + zB + d^(L-i)*FinG - xsum) * scale  -> zF
__global__ void k_fix(float* __restrict__ ws) {
    int gid = blockIdx.x * 256 + threadIdx.x;   // 524288
    int k = gid & 31;
    int t = (gid >> 5) & (SIZE - 1);
    int b = gid >> 16;
    int i = t & (CHUNK - 1);
    int c = t >> 6;
    float* zF = ws + 120064;
    const float* zB = ws + 644352;
    float finF = ws[99584 + ((b * 32 + k) << 5) + c];
    float finG = ws[99584 + 8192 + ((b * 32 + k) << 5) + c];
    float v = zF[gid] + ws[115968 + (i << 5) + k] * finF
            + zB[gid] + ws[118016 + (i << 5) + k] * finG
            - ws[256 + (b << 11) + t];
    zF[gid] = v * ws[16640 + (t << 5) + k];
}

// out[b,o,t] = sum_k y[b,t,k] * wsum[k,o]
__global__ void k_out(const float* __restrict__ ws, float* __restrict__ out) {
    __shared__ float wl[MODES * OUT_CH];
    int tid = threadIdx.x;
    for (int i = tid; i < MODES * OUT_CH; i += 256) wl[i] = ws[82176 + i];
    __syncthreads();
    int o = tid & 31;
    int row = blockIdx.x * 8 + (tid >> 5);    // row = b*SIZE + t
    const float* zy = ws + 120064 + (size_t)row * 32;
    float acc = 0.f;
#pragma unroll
    for (int k = 0; k < MODES; ++k) acc = fmaf(zy[k], wl[k * 32 + o], acc);
    int b = row >> 11, t = row & (SIZE - 1);
    out[(b * OUT_CH + o) * SIZE + t] = acc;
}

extern "C" void kernel_launch(void* const* d_in, const int* in_sizes, int n_in,
                              void* d_out, int out_size, void* d_ws, size_t ws_size,
                              hipStream_t stream) {
    const float* x      = (const float*)d_in[0];
    const float* c_star = (const float*)d_in[1];
    const float* dt     = (const float*)d_in[2];
    // d_in[3] = dx_star (unused)
    const float* wla    = (const float*)d_in[4];
    const float* wph    = (const float*)d_in[5];
    const float* lp     = (const float*)d_in[6];
    const float* pw     = (const float*)d_in[7];
    const float* pb     = (const float*)d_in[8];
    float* out = (float*)d_out;
    float* ws  = (float*)d_ws;

    k_xmean<<<32,   256,  0, stream>>>(x, ws);
    k_xsum <<<64,   256,  0, stream>>>(x, ws);
    k_prep <<<1,    64,   0, stream>>>(c_star, dt, lp, pw, pb, ws);
    k_wsum <<<1,    1024, 0, stream>>>(wla, wph, ws);
    k_scale<<<256,  256,  0, stream>>>(ws);
    k_scan <<<64,   256,  0, stream>>>(ws);
    k_carry<<<1,    512,  0, stream>>>(ws);
    k_fix  <<<2048, 256,  0, stream>>>(ws);
    k_out  <<<2048, 256,  0, stream>>>(ws, out);
}

// Round 5
// 44.709 us; speedup vs baseline: 10.7748x; 1.3852x over previous
//
#include <hip/hip_runtime.h>
#include <math.h>

#define SM1 2047.0f
#define CHUNK 64
#define NCHUNK 32

// ws float-index layout:
//   0      : poles[32]
//   32     : d[32]            d = exp(-p/2047)
//   64     : dW1[32]          d^(W+1)
//   96     : pf[32]           spectral filter
//   128    : (int) W
//   256    : wsum[32][32]     [k*32+o]
//   2048   : xmean partials [64 blocks][32 c]
//   4096   : xsum[8][2048]    (16384)
//   20480  : CF[8][32][32]    carry-in fwd  [b][k][chunk]
//   28672  : CB[8][32][32]    carry-in bwd
//   36864  : zF[8][2048][32]  chunk-local fwd scan (524288)
//   561152 : zB[8][2048][32]  chunk-local bwd scan (524288)

// K1: xsum + per-block channel partials. Reads x exactly once.
__global__ void k1(const float* __restrict__ x, float* __restrict__ ws) {
    int blk = blockIdx.x;                 // 64 blocks: b = blk>>3, s-tile = blk&7
    int b = blk >> 3;
    int s = ((blk & 7) << 8) + threadIdx.x;
    __shared__ float pr[32][4];
    int lane = threadIdx.x & 63, wid = threadIdx.x >> 6;
    float acc = 0.f;
#pragma unroll
    for (int c = 0; c < 32; ++c) {
        float v = x[(size_t)((b << 5) + c) * 2048 + s];
        acc += v;
        float r = v;
        for (int off = 32; off; off >>= 1) r += __shfl_xor(r, off);
        if (lane == 0) pr[c][wid] = r;
    }
    ws[4096 + (b << 11) + s] = acc;       // xsum
    __syncthreads();
    if (threadIdx.x < 32) {
        float m = pr[threadIdx.x][0] + pr[threadIdx.x][1] + pr[threadIdx.x][2] + pr[threadIdx.x][3];
        ws[2048 + (blk << 5) + threadIdx.x] = m;
    }
}

// K2: xmean reduce + pole prep + wsum, one block.
__global__ void k2(const float* __restrict__ c_star, const float* __restrict__ dt,
                   const float* __restrict__ log_poles, const float* __restrict__ pole_w,
                   const float* __restrict__ pole_b,
                   const float* __restrict__ wla, const float* __restrict__ wph,
                   float* __restrict__ ws) {
    __shared__ float xm[32];
    int tid = threadIdx.x;
    if (tid < 32) {
        float m = 0.f;
        for (int blk = 0; blk < 64; ++blk) m += ws[2048 + (blk << 5) + tid];
        xm[tid] = m * (1.0f / (8.0f * 2048.0f));
    }
    __syncthreads();
    if (tid < 32) {
        int k = tid;
        float mc = c_star[0];
        for (int b = 1; b < 8; ++b) mc = fmaxf(mc, c_star[b]);
        float mdn = mc * dt[0];                      // CAUSAL_SAFETY = 1
        int W = (int)(mdn * SM1);
        while (W + 1 <= 2047 && (float)(W + 1) / SM1 <= mdn) ++W;
        while (W > 0 && (float)W / SM1 > mdn) --W;
        W = min(max(W, 0), 2047);
        if (k == 0) ((int*)ws)[128] = W;
        float acc = pole_b[k];
        for (int c = 0; c < 32; ++c) acc += xm[c] * pole_w[(c << 5) + k];
        float z = log_poles[k] + 0.1f * tanhf(acc);  // POLE_OFF_SCALE
        float p = log1pf(expf(z));                   // softplus
        p = fminf(fmaxf(p, 0.1f), 100.0f);
        ws[k] = p;
        ws[32 + k] = expf(-p / SM1);
        ws[64 + k] = expf(-p * (float)(W + 1) / SM1);
        float kn = (float)k / 31.0f;
        ws[96 + k] = expf(-4.0f * kn * kn);          // FILTER_STRENGTH
    }
    // wsum[k][o] = sum_c sigmoid(wla)*cos(wph)
    int k = tid >> 5, o = tid & 31;
    float a = 0.f;
#pragma unroll 4
    for (int c = 0; c < 32; ++c) {
        int e = ((k << 5) + c) * 32 + o;
        float amp = 1.0f / (1.0f + expf(-wla[e]));
        a += amp * cosf(wph[e]);
    }
    ws[256 + tid] = a;
}

// K3: per-(b,dir) block: chunk-local scans + in-block weighted carry scan.
__global__ void k3(float* __restrict__ ws) {
    __shared__ float xr[2048];
    __shared__ float carr[NCHUNK][33];
    __shared__ float psh[32], dsh[32], dwsh[32];
    int tid = threadIdx.x;
    int b = blockIdx.x >> 1, dir = blockIdx.x & 1;
    for (int i = tid; i < 2048; i += 1024) xr[i] = ws[4096 + (b << 11) + i];
    if (tid < 32) { psh[tid] = ws[tid]; dsh[tid] = ws[32 + tid]; dwsh[tid] = ws[64 + tid]; }
    __syncthreads();
    int chunk = tid >> 5, k = tid & 31;
    int W = ((const int*)ws)[128];
    float d = dsh[k], dw = dwsh[k];
    float st = 0.f;
    float* z = ws + ((dir == 0) ? 36864 : 561152) + (((size_t)b << 11) << 5) + k;
    if (dir == 0) {
        int t0 = chunk << 6;
#pragma unroll 4
        for (int i = 0; i < CHUNK; ++i) {
            int t = t0 + i;
            float u = xr[t];
            int tl = t - W - 1;
            if (tl >= 0) u = fmaf(-dw, xr[tl], u);
            st = fmaf(d, st, u);
            z[t << 5] = st;
        }
    } else {
        int t1 = (chunk << 6) + 63;
#pragma unroll 4
        for (int i = 0; i < CHUNK; ++i) {
            int t = t1 - i;
            float u = xr[t];
            int th = t + W + 1;
            if (th <= 2047) u = fmaf(-dw, xr[th], u);
            st = fmaf(d, st, u);
            z[t << 5] = st;
        }
    }
    int sidx = (dir == 0) ? chunk : (NCHUNK - 1 - chunk);
    carr[sidx][k] = st;
    // weighted inclusive Hillis-Steele over sidx: T_s = loc_s + dL * T_{s-1}
    float m = expf(-psh[k] * (float)CHUNK / SM1);    // dL = d^CHUNK
    float cur = st;
    for (int off = 1; off < NCHUNK; off <<= 1) {
        __syncthreads();
        float prev = (sidx >= off) ? carr[sidx - off][k] : 0.f;
        __syncthreads();
        cur = fmaf(m, prev, cur);
        carr[sidx][k] = cur;
        m = m * m;
    }
    __syncthreads();
    float cin = (sidx == 0) ? 0.f : carr[sidx - 1][k];   // exclusive = carry-in
    ws[((dir == 0) ? 20480 : 28672) + (((b << 5) + k) << 5) + chunk] = cin;
}

// K4: carry fixup + inline scale + 32x32 mix + coalesced store.
__global__ void k4(const float* __restrict__ ws, float* __restrict__ out) {
    __shared__ float wl[1024];
    __shared__ float yt[32 * 33];
    __shared__ float psh[32], dsh[32], pfsh[32], cf[32], cb[32];
    int tid = threadIdx.x;
    int b = blockIdx.x >> 6;
    int t0 = (blockIdx.x & 63) << 5;   // 32 t per block, within one chunk
    int c0 = t0 >> 6;
    wl[tid] = ws[256 + tid];
    if (tid < 32) {
        psh[tid] = ws[tid]; dsh[tid] = ws[32 + tid]; pfsh[tid] = ws[96 + tid];
        cf[tid] = ws[20480 + (((b << 5) + tid) << 5) + c0];
        cb[tid] = ws[28672 + (((b << 5) + tid) << 5) + c0];
    }
    __syncthreads();
    int W = ((const int*)ws)[128];
    {
        int tt = tid >> 5, k = tid & 31;
        int t = t0 + tt;
        int i = t & 63;
        float p = psh[k], d = dsh[k];
        float zf = ws[36864 + (size_t)(((b << 11) + t) << 5) + k];
        float zb = ws[561152 + (size_t)(((b << 11) + t) << 5) + k];
        float pw1 = expf(-p * (float)(i + 1) / SM1);       // d^(i+1)
        float pw2 = expf(-p * (float)(CHUNK - i) / SM1);   // d^(L-i)
        float v = zf + pw1 * cf[k] + zb + pw2 * cb[k] - ws[4096 + (b << 11) + t];
        float den = -expm1f(-p / SM1);                     // 1-d
        int n1 = min(W, t), n2 = min(W, 2047 - t);
        float g1 = d * (-expm1f(-p * (float)n1 / SM1)) / den;
        float g2 = d * (-expm1f(-p * (float)n2 / SM1)) / den;
        yt[tt * 33 + k] = v * (pfsh[k] / (1.0f + g1 + g2));
    }
    __syncthreads();
    {
        int o = tid >> 5, tt = tid & 31;
        float acc = 0.f;
#pragma unroll
        for (int k = 0; k < 32; ++k) acc = fmaf(yt[tt * 33 + k], wl[(k << 5) + o], acc);
        out[(size_t)((b << 5) + o) * 2048 + t0 + tt] = acc;
    }
}

extern "C" void kernel_launch(void* const* d_in, const int* in_sizes, int n_in,
                              void* d_out, int out_size, void* d_ws, size_t ws_size,
                              hipStream_t stream) {
    const float* x      = (const float*)d_in[0];
    const float* c_star = (const float*)d_in[1];
    const float* dt     = (const float*)d_in[2];
    // d_in[3] = dx_star (unused)
    const float* wla    = (const float*)d_in[4];
    const float* wph    = (const float*)d_in[5];
    const float* lp     = (const float*)d_in[6];
    const float* pw     = (const float*)d_in[7];
    const float* pb     = (const float*)d_in[8];
    float* out = (float*)d_out;
    float* ws  = (float*)d_ws;

    k1<<<64,  256,  0, stream>>>(x, ws);
    k2<<<1,   1024, 0, stream>>>(c_star, dt, lp, pw, pb, wla, wph, ws);
    k3<<<16,  1024, 0, stream>>>(ws);
    k4<<<512, 1024, 0, stream>>>(ws, out);
}